// Round 7
// baseline (402.297 us; speedup 1.0000x reference)
//
#include <hip/hip_runtime.h>
#include <hip/hip_bf16.h>
#include <cstdint>
#include <cstddef>

typedef __bf16 bf16;
typedef __bf16 bf16x8 __attribute__((ext_vector_type(8)));
typedef __bf16 bf16x4 __attribute__((ext_vector_type(4)));
typedef float f32x4 __attribute__((ext_vector_type(4)));

static constexpr int BATCH = 2;
static constexpr int SEQ = 2048;
static constexpr int DMODEL = 2048;
static constexpr int NH = 16;
static constexpr int HD = 128;
static constexpr int MROWS = BATCH * SEQ; // 4096

#define GLOBAL_AS(p) ((const __attribute__((address_space(1))) void*)(p))
#define LDS_AS(p)    ((__attribute__((address_space(3))) void*)(p))

// ---------------- fused fp32 -> bf16 convert (x, Wq, Wk, Wv, Wo in one launch) ----
__global__ void cvt5_kernel(const float* __restrict__ x,
                            const float* __restrict__ wq, const float* __restrict__ wk,
                            const float* __restrict__ wv, const float* __restrict__ wo,
                            bf16* __restrict__ dst) {
  const int i = blockIdx.x * blockDim.x + threadIdx.x;   // global float4 index
  const float* src;
  int local;
  if (i < 2097152) { src = x; local = i; }
  else {
    const int r = i - 2097152;
    const int w = r >> 20;            // 0..3 (block-uniform: 4096 blocks per weight)
    local = r & 1048575;
    src = (w == 0) ? wq : (w == 1) ? wk : (w == 2) ? wv : wo;
  }
  float4 f = reinterpret_cast<const float4*>(src)[local];
  bf16x4 o;
  o.x = (bf16)f.x; o.y = (bf16)f.y; o.z = (bf16)f.z; o.w = (bf16)f.w;
  reinterpret_cast<bf16x4*>(dst)[i] = o;
}

// ---------------- QKV GEMM: proven 1536-block m97+rotation template --------------
// C = A(4096x2048,row) * W(6144x2048,row)^T ; W = [Wq;Wk;Wv] contiguous.
// 4 blocks/CU steady state (m114 implicit overlap) -> ~1016 TF measured.
__global__ __launch_bounds__(256, 4) void gemm_qkv(
    const bf16* __restrict__ A, const bf16* __restrict__ W,
    bf16* __restrict__ Oq, bf16* __restrict__ Ok, bf16* __restrict__ Ov) {
  constexpr int Kd = DMODEL;
  __shared__ __align__(16) bf16 As[128][64];
  __shared__ __align__(16) bf16 Bs[128][64];
  const int n0 = blockIdx.x * 128;
  const int m0 = blockIdx.y * 128;
  const int tid = threadIdx.x;
  const int wave = tid >> 6;
  const int lane = tid & 63;
  const int quad = lane >> 4;
  const int l16 = lane & 15;
  const int wm = (wave >> 1) * 64;
  const int wn = (wave & 1) * 64;
  const int srow = lane >> 3;                       // 0..7 within the 8-row chunk
  const int schunk = ((lane & 7) - srow) & 7;       // rotation-swizzle source chunk

  f32x4 acc[4][4] = {};
  for (int kt = 0; kt < Kd; kt += 64) {
#pragma unroll
    for (int i = 0; i < 4; i++) {
      const int r = wave * 32 + i * 8;              // r % 8 == 0
      __builtin_amdgcn_global_load_lds(
          GLOBAL_AS(&A[(size_t)(m0 + r + srow) * Kd + kt + schunk * 8]),
          LDS_AS(&As[r][0]), 16, 0, 0);
      __builtin_amdgcn_global_load_lds(
          GLOBAL_AS(&W[(size_t)(n0 + r + srow) * Kd + kt + schunk * 8]),
          LDS_AS(&Bs[r][0]), 16, 0, 0);
    }
    __syncthreads();
#pragma unroll
    for (int ks = 0; ks < 2; ks++) {
      const int col = (((ks * 4 + quad + l16) & 7)) * 8;   // swizzled read chunk
      bf16x8 af[4], bfr[4];
#pragma unroll
      for (int t = 0; t < 4; t++)
        af[t] = *reinterpret_cast<const bf16x8*>(&As[wm + t * 16 + l16][col]);
#pragma unroll
      for (int t = 0; t < 4; t++)
        bfr[t] = *reinterpret_cast<const bf16x8*>(&Bs[wn + t * 16 + l16][col]);
#pragma unroll
      for (int tm = 0; tm < 4; tm++)
#pragma unroll
        for (int tn = 0; tn < 4; tn++)
          acc[tm][tn] = __builtin_amdgcn_mfma_f32_16x16x32_bf16(af[tm], bfr[tn], acc[tm][tn], 0, 0, 0);
    }
    __syncthreads();
  }
#pragma unroll
  for (int tm = 0; tm < 4; tm++) {
#pragma unroll
    for (int tn = 0; tn < 4; tn++) {
      const int row0 = m0 + wm + tm * 16 + quad * 4;
      const int mat = n0 >> 11;              // 0=Q 1=K 2=V
      const int col = (n0 & 2047) + wn + tn * 16 + l16;
      const int h = col >> 7, dd = col & 127;
      if (mat == 2) {
        const int b = row0 >> 11, s = row0 & 2047;
        bf16x4 pk;
#pragma unroll
        for (int j = 0; j < 4; j++) pk[j] = (bf16)acc[tm][tn][j];
        *reinterpret_cast<bf16x4*>(&Ov[((size_t)(b * NH + h) * HD + dd) * SEQ + s]) = pk;
      } else {
        bf16* O = mat ? Ok : Oq;
        const float scale = mat ? 1.0f : 0.08838834764831845f;
#pragma unroll
        for (int j = 0; j < 4; j++) {
          const int row = row0 + j;
          const int b = row >> 11, s = row & 2047;
          O[((size_t)(b * NH + h) * SEQ + s) * HD + dd] = (bf16)(acc[tm][tn][j] * scale);
        }
      }
    }
  }
}

// ---------------- OUT GEMM: 64x128 tile, 24KB LDS, ~6 blocks/CU ------------------
// N=2048 gives only 512 blocks at 128^2 (2 blocks/CU -> 340 TF, the R0-R6 hidden
// 101us item). 64x128 tile -> 1024 blocks, 24KB LDS -> 6 blocks/CU restores the
// m114 multi-block overlap. Same rotation swizzle + fragment math; wave grid 2x2,
// per-wave 32x64 output (acc[2][4]).
__global__ __launch_bounds__(256, 6) void gemm_out64(
    const bf16* __restrict__ A, const bf16* __restrict__ W,
    float* __restrict__ Oout) {
  constexpr int Kd = DMODEL;
  __shared__ __align__(16) bf16 As[64][64];     //  8 KB
  __shared__ __align__(16) bf16 Bs[128][64];    // 16 KB
  const int n0 = blockIdx.x * 128;
  const int m0 = blockIdx.y * 64;
  const int tid = threadIdx.x;
  const int wave = tid >> 6;
  const int lane = tid & 63;
  const int quad = lane >> 4;
  const int l16 = lane & 15;
  const int wm = (wave >> 1) * 32;   // 2 M-halves (32 rows each)
  const int wn = (wave & 1) * 64;    // 2 N-halves (64 cols each)
  const int srow = lane >> 3;
  const int schunk = ((lane & 7) - srow) & 7;

  f32x4 acc[2][4] = {};
  for (int kt = 0; kt < Kd; kt += 64) {
#pragma unroll
    for (int i = 0; i < 2; i++) {
      const int r = wave * 16 + i * 8;              // rows 0..56 step 8 (A: 64 rows)
      __builtin_amdgcn_global_load_lds(
          GLOBAL_AS(&A[(size_t)(m0 + r + srow) * Kd + kt + schunk * 8]),
          LDS_AS(&As[r][0]), 16, 0, 0);
    }
#pragma unroll
    for (int i = 0; i < 4; i++) {
      const int r = wave * 32 + i * 8;              // rows 0..120 step 8 (B: 128 rows)
      __builtin_amdgcn_global_load_lds(
          GLOBAL_AS(&W[(size_t)(n0 + r + srow) * Kd + kt + schunk * 8]),
          LDS_AS(&Bs[r][0]), 16, 0, 0);
    }
    __syncthreads();
#pragma unroll
    for (int ks = 0; ks < 2; ks++) {
      const int col = (((ks * 4 + quad + l16) & 7)) * 8;
      bf16x8 af[2], bfr[4];
#pragma unroll
      for (int t = 0; t < 2; t++)
        af[t] = *reinterpret_cast<const bf16x8*>(&As[wm + t * 16 + l16][col]);
#pragma unroll
      for (int t = 0; t < 4; t++)
        bfr[t] = *reinterpret_cast<const bf16x8*>(&Bs[wn + t * 16 + l16][col]);
#pragma unroll
      for (int tm = 0; tm < 2; tm++)
#pragma unroll
        for (int tn = 0; tn < 4; tn++)
          acc[tm][tn] = __builtin_amdgcn_mfma_f32_16x16x32_bf16(af[tm], bfr[tn], acc[tm][tn], 0, 0, 0);
    }
    __syncthreads();
  }
#pragma unroll
  for (int tm = 0; tm < 2; tm++) {
#pragma unroll
    for (int tn = 0; tn < 4; tn++) {
      const int row0 = m0 + wm + tm * 16 + quad * 4;
      const int col = n0 + wn + tn * 16 + l16;
#pragma unroll
      for (int j = 0; j < 4; j++)
        Oout[(size_t)(row0 + j) * DMODEL + col] = acc[tm][tn][j];
    }
  }
}

// ---------------- flash attention: R1 internals + XCD-grouped block decode -------
// 512 blocks = 2/CU exactly co-resident. Decode pins all 16 j-blocks of a bh
// (plus 3 partner bh) to one XCD: per-XCD K/V working set = 4 x 1MB = one L2.
// Targets the measured 258MB FETCH_SIZE (L2 thrash across XCDs).
__global__ __launch_bounds__(256, 2) void attn_kernel(
    const bf16* __restrict__ Q, const bf16* __restrict__ K,
    const bf16* __restrict__ Vt, bf16* __restrict__ Y) {
  const int lin = blockIdx.x;        // 0..511
  const int xcd = lin & 7;           // dispatch round-robins linear id over XCDs
  const int within = lin >> 3;       // 0..63
  const int j = within & 15;         // q-block pair index (j, 31-j)
  const int bh = xcd + 8 * (within >> 4);   // 4 bh per XCD
  __shared__ __align__(16) char smem[74752];
  auto Ks0 = (bf16(*)[128])(smem);              // [64][128] 16384 B (swizzled)
  auto Ks1 = (bf16(*)[128])(smem + 16384);
  auto Vt0 = (bf16(*)[64])(smem + 32768);       // [128][64] 16384 B (swizzled)
  auto Vt1 = (bf16(*)[64])(smem + 49152);
  auto Ps  = (bf16(*)[16][72])(smem + 65536);   // [4][16][72] 9216 B (padded)
  const int tid = threadIdx.x;
  const int wave = tid >> 6;
  const int lane = tid & 63;
  const int quad = lane >> 4;
  const int l16 = lane & 15;

  const bf16* Kbh = K + (size_t)bh * SEQ * HD;
  const bf16* Vbh = Vt + (size_t)bh * HD * SEQ;
  const int b = bh >> 4, h = bh & 15;

  const int krow = lane >> 4;
  const int vrow = lane >> 3;
  const int vchunk = ((lane & 7) - vrow) & 7;

  auto stageK = [&](int kt, bf16 (*Kd)[128]) {
#pragma unroll
    for (int i = 0; i < 4; i++) {
      const int rbase = wave * 16 + i * 4;
      const int r = rbase + krow;
      const int c = ((lane & 15) - krow - i * 4) & 15;
      __builtin_amdgcn_global_load_lds(
          GLOBAL_AS(&Kbh[(size_t)(kt + r) * HD + c * 8]), LDS_AS(&Kd[rbase][0]), 16, 0, 0);
    }
  };
  auto stageV = [&](int kt, bf16 (*Vd)[64]) {
#pragma unroll
    for (int i = 0; i < 4; i++) {
      const int rbase = wave * 32 + i * 8;
      const int r = rbase + vrow;
      __builtin_amdgcn_global_load_lds(
          GLOBAL_AS(&Vbh[(size_t)r * SEQ + kt + vchunk * 8]), LDS_AS(&Vd[rbase][0]), 16, 0, 0);
    }
  };

  for (int pass = 0; pass < 2; ++pass) {
    const int qt = pass ? (31 - j) : j;
    const int q0 = qt * 64;
    const int ntiles = qt + 1;

    const bf16* Qw = Q + ((size_t)bh * SEQ + q0 + wave * 16) * HD;
    bf16x8 qf[4];
#pragma unroll
    for (int kk = 0; kk < 4; kk++)
      qf[kk] = *reinterpret_cast<const bf16x8*>(&Qw[(size_t)l16 * HD + kk * 32 + quad * 8]);

    f32x4 oacc[8] = {};
    float m_i = -3.0e38f, l_i = 0.f;

    stageK(0, Ks0);
    stageV(0, Vt0);
    asm volatile("s_waitcnt vmcnt(0)" ::: "memory");
    __builtin_amdgcn_s_barrier();
    __builtin_amdgcn_sched_barrier(0);

    for (int t = 0; t < ntiles; ++t) {
      bf16 (*Ksc)[128] = (t & 1) ? Ks1 : Ks0;
      bf16 (*Vtc)[64]  = (t & 1) ? Vt1 : Vt0;
      if (t + 1 < ntiles) {
        bf16 (*Ksn)[128] = (t & 1) ? Ks0 : Ks1;
        bf16 (*Vtn)[64]  = (t & 1) ? Vt0 : Vt1;
        stageK((t + 1) * 64, Ksn);
        stageV((t + 1) * 64, Vtn);
      }

      f32x4 sacc[4] = {};
#pragma unroll
      for (int kk = 0; kk < 4; kk++) {
        const int kcol = (((kk * 4 + quad + l16) & 15)) * 8;
        bf16x8 ka[4];
#pragma unroll
        for (int mt = 0; mt < 4; mt++)
          ka[mt] = *reinterpret_cast<const bf16x8*>(&Ksc[mt * 16 + l16][kcol]);
#pragma unroll
        for (int mt = 0; mt < 4; mt++)
          sacc[mt] = __builtin_amdgcn_mfma_f32_16x16x32_bf16(ka[mt], qf[kk], sacc[mt], 0, 0, 0);
      }

      const int qg_loc = wave * 16 + l16;
      float mx = -3.0e38f;
      if (t == ntiles - 1) {
#pragma unroll
        for (int mt = 0; mt < 4; mt++)
#pragma unroll
          for (int jj = 0; jj < 4; jj++) {
            const int kg = mt * 16 + quad * 4 + jj;
            float v = (kg <= qg_loc) ? sacc[mt][jj] : -3.0e38f;
            sacc[mt][jj] = v;
            mx = fmaxf(mx, v);
          }
      } else {
#pragma unroll
        for (int mt = 0; mt < 4; mt++)
#pragma unroll
          for (int jj = 0; jj < 4; jj++) mx = fmaxf(mx, sacc[mt][jj]);
      }
      mx = fmaxf(mx, __shfl_xor(mx, 16));
      mx = fmaxf(mx, __shfl_xor(mx, 32));
      const float mnew = fmaxf(m_i, mx);
      const float alpha = __expf(m_i - mnew);
      m_i = mnew;
      float rs = 0.f;
#pragma unroll
      for (int mt = 0; mt < 4; mt++)
#pragma unroll
        for (int jj = 0; jj < 4; jj++) {
          float p = __expf(sacc[mt][jj] - mnew);
          sacc[mt][jj] = p;
          rs += p;
        }
      rs += __shfl_xor(rs, 16);
      rs += __shfl_xor(rs, 32);
      l_i = l_i * alpha + rs;
#pragma unroll
      for (int mt8 = 0; mt8 < 8; mt8++)
#pragma unroll
        for (int jj = 0; jj < 4; jj++) oacc[mt8][jj] *= alpha;

#pragma unroll
      for (int mt = 0; mt < 4; mt++) {
        bf16x4 pk;
#pragma unroll
        for (int jj = 0; jj < 4; jj++) pk[jj] = (bf16)sacc[mt][jj];
        *reinterpret_cast<bf16x4*>(&Ps[wave][l16][mt * 16 + quad * 4]) = pk;
      }

#pragma unroll
      for (int kk2 = 0; kk2 < 2; kk2++) {
        const int vcol = ((kk2 * 4 + quad + l16) & 7) * 8;
        bf16x8 pb = *reinterpret_cast<const bf16x8*>(&Ps[wave][l16][kk2 * 32 + quad * 8]);
#pragma unroll
        for (int mt8 = 0; mt8 < 8; mt8++) {
          bf16x8 av = *reinterpret_cast<const bf16x8*>(&Vtc[mt8 * 16 + l16][vcol]);
          oacc[mt8] = __builtin_amdgcn_mfma_f32_16x16x32_bf16(av, pb, oacc[mt8], 0, 0, 0);
        }
      }

      asm volatile("s_waitcnt vmcnt(0)" ::: "memory");
      __builtin_amdgcn_s_barrier();
      __builtin_amdgcn_sched_barrier(0);
    }

    const float inv = 1.0f / l_i;
    const int qg = q0 + wave * 16 + l16;
#pragma unroll
    for (int mt8 = 0; mt8 < 8; mt8++) {
      bf16x4 pk;
#pragma unroll
      for (int jj = 0; jj < 4; jj++) pk[jj] = (bf16)(oacc[mt8][jj] * inv);
      *reinterpret_cast<bf16x4*>(
          &Y[(size_t)(b * SEQ + qg) * DMODEL + h * HD + mt8 * 16 + quad * 4]) = pk;
    }
  }
}

// ---------------- launch ----------------
extern "C" void kernel_launch(void* const* d_in, const int* in_sizes, int n_in,
                              void* d_out, int out_size, void* d_ws, size_t ws_size,
                              hipStream_t stream) {
  const float* x  = (const float*)d_in[0];
  const float* Wq = (const float*)d_in[2];
  const float* Wk = (const float*)d_in[3];
  const float* Wv = (const float*)d_in[4];
  const float* Wo = (const float*)d_in[5];
  float* out = (float*)d_out;

  char* ws = (char*)d_ws;
  bf16* xb  = (bf16*)(ws + 0);
  bf16* Wqb = (bf16*)(ws + 16777216);    // Wq,Wk,Wv contiguous -> one [6144][2048]
  bf16* Wob = (bf16*)(ws + 41943040);
  bf16* Qb  = (bf16*)(ws + 50331648);    // [B,H,S,d]
  bf16* Kb  = (bf16*)(ws + 67108864);    // [B,H,S,d]
  bf16* Vtb = (bf16*)(ws + 83886080);    // [B,H,d,S]
  bf16* Yb  = xb;                        // [B,S,D] (x dead after projections)
  if (ws_size < 100663296) return;

  // one fused convert: 6,291,456 float4 groups -> 24576 blocks
  cvt5_kernel<<<24576, 256, 0, stream>>>(x, Wq, Wk, Wv, Wo, xb);

  gemm_qkv<<<dim3(48, MROWS / 128), 256, 0, stream>>>(
      xb, Wqb, Qb, Kb, Vtb);

  attn_kernel<<<512, 256, 0, stream>>>(Qb, Kb, Vtb, Yb);

  gemm_out64<<<dim3(16, MROWS / 64), 256, 0, stream>>>(
      Yb, Wob, out);
}

// Round 8
// 381.009 us; speedup vs baseline: 1.0559x; 1.0559x over previous
//
#include <hip/hip_runtime.h>
#include <hip/hip_bf16.h>
#include <cstdint>
#include <cstddef>

typedef __bf16 bf16;
typedef __bf16 bf16x8 __attribute__((ext_vector_type(8)));
typedef __bf16 bf16x4 __attribute__((ext_vector_type(4)));
typedef float f32x4 __attribute__((ext_vector_type(4)));

static constexpr int BATCH = 2;
static constexpr int SEQ = 2048;
static constexpr int DMODEL = 2048;
static constexpr int NH = 16;
static constexpr int HD = 128;
static constexpr int MROWS = BATCH * SEQ; // 4096

#define GLOBAL_AS(p) ((const __attribute__((address_space(1))) void*)(p))
#define LDS_AS(p)    ((__attribute__((address_space(3))) void*)(p))

// ---------------- fused fp32 -> bf16 convert (x, Wq, Wk, Wv, Wo in one launch) ----
__global__ void cvt5_kernel(const float* __restrict__ x,
                            const float* __restrict__ wq, const float* __restrict__ wk,
                            const float* __restrict__ wv, const float* __restrict__ wo,
                            bf16* __restrict__ dst) {
  const int i = blockIdx.x * blockDim.x + threadIdx.x;   // global float4 index
  const float* src;
  int local;
  if (i < 2097152) { src = x; local = i; }
  else {
    const int r = i - 2097152;
    const int w = r >> 20;            // 0..3 (block-uniform: 4096 blocks per weight)
    local = r & 1048575;
    src = (w == 0) ? wq : (w == 1) ? wk : (w == 2) ? wv : wo;
  }
  float4 f = reinterpret_cast<const float4*>(src)[local];
  bf16x4 o;
  o.x = (bf16)f.x; o.y = (bf16)f.y; o.z = (bf16)f.z; o.w = (bf16)f.w;
  reinterpret_cast<bf16x4*>(dst)[i] = o;
}

// ---------------- QKV GEMM: proven 1536-block m97+rotation template --------------
// C = A(4096x2048,row) * W(6144x2048,row)^T ; W = [Wq;Wk;Wv] contiguous.
// 4 blocks/CU steady state (m114 implicit overlap) -> ~1016 TF measured.
__global__ __launch_bounds__(256, 4) void gemm_qkv(
    const bf16* __restrict__ A, const bf16* __restrict__ W,
    bf16* __restrict__ Oq, bf16* __restrict__ Ok, bf16* __restrict__ Ov) {
  constexpr int Kd = DMODEL;
  __shared__ __align__(16) bf16 As[128][64];
  __shared__ __align__(16) bf16 Bs[128][64];
  const int n0 = blockIdx.x * 128;
  const int m0 = blockIdx.y * 128;
  const int tid = threadIdx.x;
  const int wave = tid >> 6;
  const int lane = tid & 63;
  const int quad = lane >> 4;
  const int l16 = lane & 15;
  const int wm = (wave >> 1) * 64;
  const int wn = (wave & 1) * 64;
  const int srow = lane >> 3;                       // 0..7 within the 8-row chunk
  const int schunk = ((lane & 7) - srow) & 7;       // rotation-swizzle source chunk

  f32x4 acc[4][4] = {};
  for (int kt = 0; kt < Kd; kt += 64) {
#pragma unroll
    for (int i = 0; i < 4; i++) {
      const int r = wave * 32 + i * 8;              // r % 8 == 0
      __builtin_amdgcn_global_load_lds(
          GLOBAL_AS(&A[(size_t)(m0 + r + srow) * Kd + kt + schunk * 8]),
          LDS_AS(&As[r][0]), 16, 0, 0);
      __builtin_amdgcn_global_load_lds(
          GLOBAL_AS(&W[(size_t)(n0 + r + srow) * Kd + kt + schunk * 8]),
          LDS_AS(&Bs[r][0]), 16, 0, 0);
    }
    __syncthreads();
#pragma unroll
    for (int ks = 0; ks < 2; ks++) {
      const int col = (((ks * 4 + quad + l16) & 7)) * 8;   // swizzled read chunk
      bf16x8 af[4], bfr[4];
#pragma unroll
      for (int t = 0; t < 4; t++)
        af[t] = *reinterpret_cast<const bf16x8*>(&As[wm + t * 16 + l16][col]);
#pragma unroll
      for (int t = 0; t < 4; t++)
        bfr[t] = *reinterpret_cast<const bf16x8*>(&Bs[wn + t * 16 + l16][col]);
#pragma unroll
      for (int tm = 0; tm < 4; tm++)
#pragma unroll
        for (int tn = 0; tn < 4; tn++)
          acc[tm][tn] = __builtin_amdgcn_mfma_f32_16x16x32_bf16(af[tm], bfr[tn], acc[tm][tn], 0, 0, 0);
    }
    __syncthreads();
  }
#pragma unroll
  for (int tm = 0; tm < 4; tm++) {
#pragma unroll
    for (int tn = 0; tn < 4; tn++) {
      const int row0 = m0 + wm + tm * 16 + quad * 4;
      const int mat = n0 >> 11;              // 0=Q 1=K 2=V
      const int col = (n0 & 2047) + wn + tn * 16 + l16;
      const int h = col >> 7, dd = col & 127;
      if (mat == 2) {
        const int b = row0 >> 11, s = row0 & 2047;
        bf16x4 pk;
#pragma unroll
        for (int j = 0; j < 4; j++) pk[j] = (bf16)acc[tm][tn][j];
        *reinterpret_cast<bf16x4*>(&Ov[((size_t)(b * NH + h) * HD + dd) * SEQ + s]) = pk;
      } else {
        bf16* O = mat ? Ok : Oq;
        const float scale = mat ? 1.0f : 0.08838834764831845f;
#pragma unroll
        for (int j = 0; j < 4; j++) {
          const int row = row0 + j;
          const int b = row >> 11, s = row & 2047;
          O[((size_t)(b * NH + h) * SEQ + s) * HD + dd] = (bf16)(acc[tm][tn][j] * scale);
        }
      }
    }
  }
}

// ---------------- OUT GEMM: split-K=2, 1024 blocks (4/CU), f32 partials ----------
// Same 128^2 template/intensity as gemm_qkv; z selects K-half [z*1024, z*1024+1024).
// Partials land in DEAD ws regions (Wq/Wk/Wv after QKV; Q/K/V after attn):
//   P0  (z=0, 32MB) @ Qb;  P1a (z=1 rows<3072, 24MB) @ Wqb;  P1b (rows>=3072, 8MB) @ Vtb.
// Deterministic (no atomics); reduce_out sums. Block's rows never straddle 3072.
__global__ __launch_bounds__(256, 4) void gemm_out_sk(
    const bf16* __restrict__ A, const bf16* __restrict__ W,
    float* __restrict__ P0, float* __restrict__ P1a, float* __restrict__ P1b) {
  __shared__ __align__(16) bf16 As[128][64];
  __shared__ __align__(16) bf16 Bs[128][64];
  const int n0 = blockIdx.x * 128;
  const int m0 = blockIdx.y * 128;
  const int kz = blockIdx.z * 1024;
  const int tid = threadIdx.x;
  const int wave = tid >> 6;
  const int lane = tid & 63;
  const int quad = lane >> 4;
  const int l16 = lane & 15;
  const int wm = (wave >> 1) * 64;
  const int wn = (wave & 1) * 64;
  const int srow = lane >> 3;
  const int schunk = ((lane & 7) - srow) & 7;

  f32x4 acc[4][4] = {};
  for (int kt = kz; kt < kz + 1024; kt += 64) {
#pragma unroll
    for (int i = 0; i < 4; i++) {
      const int r = wave * 32 + i * 8;
      __builtin_amdgcn_global_load_lds(
          GLOBAL_AS(&A[(size_t)(m0 + r + srow) * DMODEL + kt + schunk * 8]),
          LDS_AS(&As[r][0]), 16, 0, 0);
      __builtin_amdgcn_global_load_lds(
          GLOBAL_AS(&W[(size_t)(n0 + r + srow) * DMODEL + kt + schunk * 8]),
          LDS_AS(&Bs[r][0]), 16, 0, 0);
    }
    __syncthreads();
#pragma unroll
    for (int ks = 0; ks < 2; ks++) {
      const int col = (((ks * 4 + quad + l16) & 7)) * 8;
      bf16x8 af[4], bfr[4];
#pragma unroll
      for (int t = 0; t < 4; t++)
        af[t] = *reinterpret_cast<const bf16x8*>(&As[wm + t * 16 + l16][col]);
#pragma unroll
      for (int t = 0; t < 4; t++)
        bfr[t] = *reinterpret_cast<const bf16x8*>(&Bs[wn + t * 16 + l16][col]);
#pragma unroll
      for (int tm = 0; tm < 4; tm++)
#pragma unroll
        for (int tn = 0; tn < 4; tn++)
          acc[tm][tn] = __builtin_amdgcn_mfma_f32_16x16x32_bf16(af[tm], bfr[tn], acc[tm][tn], 0, 0, 0);
    }
    __syncthreads();
  }
#pragma unroll
  for (int tm = 0; tm < 4; tm++) {
#pragma unroll
    for (int tn = 0; tn < 4; tn++) {
      const int row0 = m0 + wm + tm * 16 + quad * 4;
      const int col = n0 + wn + tn * 16 + l16;
      if (blockIdx.z == 0) {
#pragma unroll
        for (int j = 0; j < 4; j++)
          P0[(size_t)(row0 + j) * DMODEL + col] = acc[tm][tn][j];
      } else if (row0 < 3072) {
#pragma unroll
        for (int j = 0; j < 4; j++)
          P1a[(size_t)(row0 + j) * DMODEL + col] = acc[tm][tn][j];
      } else {
#pragma unroll
        for (int j = 0; j < 4; j++)
          P1b[(size_t)(row0 - 3072 + j) * DMODEL + col] = acc[tm][tn][j];
      }
    }
  }
}

// ---------------- reduce: out = P0 + P1 (vectorized, 8192 blocks) ----------------
__global__ void reduce_out(const float* __restrict__ P0, const float* __restrict__ P1a,
                           const float* __restrict__ P1b, float* __restrict__ out) {
  const int i = blockIdx.x * blockDim.x + threadIdx.x;   // f32x4 index, 2,097,152 total
  const int e = i * 4;
  const int row = e >> 11;
  f32x4 a = *reinterpret_cast<const f32x4*>(&P0[e]);
  f32x4 b = (row < 3072) ? *reinterpret_cast<const f32x4*>(&P1a[e])
                         : *reinterpret_cast<const f32x4*>(&P1b[e - 3072 * 2048]);
  f32x4 c = a + b;
  *reinterpret_cast<f32x4*>(&out[e]) = c;
}

// ---------------- flash attention: R1 structure (QBLK=64, dbuf, two passes) ----
__global__ __launch_bounds__(256, 2) void attn_kernel(
    const bf16* __restrict__ Q, const bf16* __restrict__ K,
    const bf16* __restrict__ Vt, bf16* __restrict__ Y) {
  const int j = blockIdx.x;          // 0..15
  const int bh = blockIdx.y;
  __shared__ __align__(16) char smem[74752];
  auto Ks0 = (bf16(*)[128])(smem);              // [64][128] 16384 B (swizzled)
  auto Ks1 = (bf16(*)[128])(smem + 16384);
  auto Vt0 = (bf16(*)[64])(smem + 32768);       // [128][64] 16384 B (swizzled)
  auto Vt1 = (bf16(*)[64])(smem + 49152);
  auto Ps  = (bf16(*)[16][72])(smem + 65536);   // [4][16][72] 9216 B (padded)
  const int tid = threadIdx.x;
  const int wave = tid >> 6;
  const int lane = tid & 63;
  const int quad = lane >> 4;
  const int l16 = lane & 15;

  const bf16* Kbh = K + (size_t)bh * SEQ * HD;
  const bf16* Vbh = Vt + (size_t)bh * HD * SEQ;
  const int b = bh >> 4, h = bh & 15;

  const int krow = lane >> 4;
  const int vrow = lane >> 3;
  const int vchunk = ((lane & 7) - vrow) & 7;

  auto stageK = [&](int kt, bf16 (*Kd)[128]) {
#pragma unroll
    for (int i = 0; i < 4; i++) {
      const int rbase = wave * 16 + i * 4;
      const int r = rbase + krow;
      const int c = ((lane & 15) - krow - i * 4) & 15;
      __builtin_amdgcn_global_load_lds(
          GLOBAL_AS(&Kbh[(size_t)(kt + r) * HD + c * 8]), LDS_AS(&Kd[rbase][0]), 16, 0, 0);
    }
  };
  auto stageV = [&](int kt, bf16 (*Vd)[64]) {
#pragma unroll
    for (int i = 0; i < 4; i++) {
      const int rbase = wave * 32 + i * 8;
      const int r = rbase + vrow;
      __builtin_amdgcn_global_load_lds(
          GLOBAL_AS(&Vbh[(size_t)r * SEQ + kt + vchunk * 8]), LDS_AS(&Vd[rbase][0]), 16, 0, 0);
    }
  };

  for (int pass = 0; pass < 2; ++pass) {
    const int qt = pass ? (31 - j) : j;
    const int q0 = qt * 64;
    const int ntiles = qt + 1;

    const bf16* Qw = Q + ((size_t)bh * SEQ + q0 + wave * 16) * HD;
    bf16x8 qf[4];
#pragma unroll
    for (int kk = 0; kk < 4; kk++)
      qf[kk] = *reinterpret_cast<const bf16x8*>(&Qw[(size_t)l16 * HD + kk * 32 + quad * 8]);

    f32x4 oacc[8] = {};
    float m_i = -3.0e38f, l_i = 0.f;

    stageK(0, Ks0);
    stageV(0, Vt0);
    asm volatile("s_waitcnt vmcnt(0)" ::: "memory");
    __builtin_amdgcn_s_barrier();
    __builtin_amdgcn_sched_barrier(0);

    for (int t = 0; t < ntiles; ++t) {
      bf16 (*Ksc)[128] = (t & 1) ? Ks1 : Ks0;
      bf16 (*Vtc)[64]  = (t & 1) ? Vt1 : Vt0;
      if (t + 1 < ntiles) {
        bf16 (*Ksn)[128] = (t & 1) ? Ks0 : Ks1;
        bf16 (*Vtn)[64]  = (t & 1) ? Vt0 : Vt1;
        stageK((t + 1) * 64, Ksn);
        stageV((t + 1) * 64, Vtn);
      }

      f32x4 sacc[4] = {};
#pragma unroll
      for (int kk = 0; kk < 4; kk++) {
        const int kcol = (((kk * 4 + quad + l16) & 15)) * 8;
        bf16x8 ka[4];
#pragma unroll
        for (int mt = 0; mt < 4; mt++)
          ka[mt] = *reinterpret_cast<const bf16x8*>(&Ksc[mt * 16 + l16][kcol]);
#pragma unroll
        for (int mt = 0; mt < 4; mt++)
          sacc[mt] = __builtin_amdgcn_mfma_f32_16x16x32_bf16(ka[mt], qf[kk], sacc[mt], 0, 0, 0);
      }

      const int qg_loc = wave * 16 + l16;
      float mx = -3.0e38f;
      if (t == ntiles - 1) {
#pragma unroll
        for (int mt = 0; mt < 4; mt++)
#pragma unroll
          for (int jj = 0; jj < 4; jj++) {
            const int kg = mt * 16 + quad * 4 + jj;
            float v = (kg <= qg_loc) ? sacc[mt][jj] : -3.0e38f;
            sacc[mt][jj] = v;
            mx = fmaxf(mx, v);
          }
      } else {
#pragma unroll
        for (int mt = 0; mt < 4; mt++)
#pragma unroll
          for (int jj = 0; jj < 4; jj++) mx = fmaxf(mx, sacc[mt][jj]);
      }
      mx = fmaxf(mx, __shfl_xor(mx, 16));
      mx = fmaxf(mx, __shfl_xor(mx, 32));
      const float mnew = fmaxf(m_i, mx);
      const float alpha = __expf(m_i - mnew);
      m_i = mnew;
      float rs = 0.f;
#pragma unroll
      for (int mt = 0; mt < 4; mt++)
#pragma unroll
        for (int jj = 0; jj < 4; jj++) {
          float p = __expf(sacc[mt][jj] - mnew);
          sacc[mt][jj] = p;
          rs += p;
        }
      rs += __shfl_xor(rs, 16);
      rs += __shfl_xor(rs, 32);
      l_i = l_i * alpha + rs;
#pragma unroll
      for (int mt8 = 0; mt8 < 8; mt8++)
#pragma unroll
        for (int jj = 0; jj < 4; jj++) oacc[mt8][jj] *= alpha;

#pragma unroll
      for (int mt = 0; mt < 4; mt++) {
        bf16x4 pk;
#pragma unroll
        for (int jj = 0; jj < 4; jj++) pk[jj] = (bf16)sacc[mt][jj];
        *reinterpret_cast<bf16x4*>(&Ps[wave][l16][mt * 16 + quad * 4]) = pk;
      }

#pragma unroll
      for (int kk2 = 0; kk2 < 2; kk2++) {
        const int vcol = ((kk2 * 4 + quad + l16) & 7) * 8;
        bf16x8 pb = *reinterpret_cast<const bf16x8*>(&Ps[wave][l16][kk2 * 32 + quad * 8]);
#pragma unroll
        for (int mt8 = 0; mt8 < 8; mt8++) {
          bf16x8 av = *reinterpret_cast<const bf16x8*>(&Vtc[mt8 * 16 + l16][vcol]);
          oacc[mt8] = __builtin_amdgcn_mfma_f32_16x16x32_bf16(av, pb, oacc[mt8], 0, 0, 0);
        }
      }

      asm volatile("s_waitcnt vmcnt(0)" ::: "memory");
      __builtin_amdgcn_s_barrier();
      __builtin_amdgcn_sched_barrier(0);
    }

    const float inv = 1.0f / l_i;
    const int qg = q0 + wave * 16 + l16;
#pragma unroll
    for (int mt8 = 0; mt8 < 8; mt8++) {
      bf16x4 pk;
#pragma unroll
      for (int jj = 0; jj < 4; jj++) pk[jj] = (bf16)(oacc[mt8][jj] * inv);
      *reinterpret_cast<bf16x4*>(
          &Y[(size_t)(b * SEQ + qg) * DMODEL + h * HD + mt8 * 16 + quad * 4]) = pk;
    }
  }
}

// ---------------- launch ----------------
extern "C" void kernel_launch(void* const* d_in, const int* in_sizes, int n_in,
                              void* d_out, int out_size, void* d_ws, size_t ws_size,
                              hipStream_t stream) {
  const float* x  = (const float*)d_in[0];
  const float* Wq = (const float*)d_in[2];
  const float* Wk = (const float*)d_in[3];
  const float* Wv = (const float*)d_in[4];
  const float* Wo = (const float*)d_in[5];
  float* out = (float*)d_out;

  char* ws = (char*)d_ws;
  bf16* xb  = (bf16*)(ws + 0);
  bf16* Wqb = (bf16*)(ws + 16777216);    // Wq,Wk,Wv contiguous -> one [6144][2048]
  bf16* Wob = (bf16*)(ws + 41943040);
  bf16* Qb  = (bf16*)(ws + 50331648);    // [B,H,S,d]
  bf16* Kb  = (bf16*)(ws + 67108864);    // [B,H,S,d]
  bf16* Vtb = (bf16*)(ws + 83886080);    // [B,H,d,S]
  bf16* Yb  = xb;                        // [B,S,D] (x dead after projections)
  // split-K partial buffers -- all in regions DEAD by the time gemm_out_sk runs:
  float* P0  = (float*)(ws + 50331648);  // 32 MB over Qb+Kb (dead after attn)
  float* P1a = (float*)(ws + 16777216);  // 24 MB over Wqb/Wkb/Wvb (dead after QKV)
  float* P1b = (float*)(ws + 83886080);  //  8 MB over Vtb (dead after attn)
  if (ws_size < 100663296) return;

  // one fused convert: 6,291,456 float4 groups -> 24576 blocks
  cvt5_kernel<<<24576, 256, 0, stream>>>(x, Wq, Wk, Wv, Wo, xb);

  gemm_qkv<<<dim3(48, MROWS / 128), 256, 0, stream>>>(
      xb, Wqb, Qb, Kb, Vtb);

  attn_kernel<<<dim3(16, BATCH * NH), 256, 0, stream>>>(Qb, Kb, Vtb, Yb);

  gemm_out_sk<<<dim3(16, MROWS / 128, 2), 256, 0, stream>>>(
      Yb, Wob, P0, P1a, P1b);

  reduce_out<<<8192, 256, 0, stream>>>(P0, P1a, P1b, out);
}

// Round 10
// 371.004 us; speedup vs baseline: 1.0843x; 1.0270x over previous
//
#include <hip/hip_runtime.h>
#include <hip/hip_bf16.h>
#include <cstdint>
#include <cstddef>

typedef __bf16 bf16;
typedef __bf16 bf16x8 __attribute__((ext_vector_type(8)));
typedef __bf16 bf16x4 __attribute__((ext_vector_type(4)));
typedef float f32x4 __attribute__((ext_vector_type(4)));

static constexpr int BATCH = 2;
static constexpr int SEQ = 2048;
static constexpr int DMODEL = 2048;
static constexpr int NH = 16;
static constexpr int HD = 128;
static constexpr int MROWS = BATCH * SEQ; // 4096

#define GLOBAL_AS(p) ((const __attribute__((address_space(1))) void*)(p))
#define LDS_AS(p)    ((__attribute__((address_space(3))) void*)(p))

// ---------------- fused fp32 -> bf16 convert (x, Wq, Wk, Wv, Wo in one launch) ----
__global__ void cvt5_kernel(const float* __restrict__ x,
                            const float* __restrict__ wq, const float* __restrict__ wk,
                            const float* __restrict__ wv, const float* __restrict__ wo,
                            bf16* __restrict__ dst) {
  const int i = blockIdx.x * blockDim.x + threadIdx.x;   // global float4 index
  const float* src;
  int local;
  if (i < 2097152) { src = x; local = i; }
  else {
    const int r = i - 2097152;
    const int w = r >> 20;            // 0..3 (block-uniform: 4096 blocks per weight)
    local = r & 1048575;
    src = (w == 0) ? wq : (w == 1) ? wk : (w == 2) ? wv : wo;
  }
  float4 f = reinterpret_cast<const float4*>(src)[local];
  bf16x4 o;
  o.x = (bf16)f.x; o.y = (bf16)f.y; o.z = (bf16)f.z; o.w = (bf16)f.w;
  reinterpret_cast<bf16x4*>(dst)[i] = o;
}

// ---------------- GEMM: C = A(MxK,row) * W(NxK,row)^T ----------------
// m97 structure + rotation swizzle: row r's 16B-chunk c stored at chunk (c+r)&7.
// Q-scale carries log2(e) for the exp2-domain softmax:
//   0.08838834764831845 * 1.4426950408889634 = 0.12751745
enum { MODE_QKV = 0, MODE_OUT = 1 };

template <int MODE>
__global__ __launch_bounds__(256, 4) void gemm_bt(
    const bf16* __restrict__ A, const bf16* __restrict__ W,
    bf16* __restrict__ Oq, bf16* __restrict__ Ok, bf16* __restrict__ Ov,
    float* __restrict__ Oout) {
  constexpr int Kd = DMODEL;
  __shared__ __align__(16) bf16 As[128][64];
  __shared__ __align__(16) bf16 Bs[128][64];
  const int n0 = blockIdx.x * 128;
  const int m0 = blockIdx.y * 128;
  const int tid = threadIdx.x;
  const int wave = tid >> 6;
  const int lane = tid & 63;
  const int quad = lane >> 4;
  const int l16 = lane & 15;
  const int wm = (wave >> 1) * 64;
  const int wn = (wave & 1) * 64;
  const int srow = lane >> 3;                       // 0..7 within the 8-row chunk
  const int schunk = ((lane & 7) - srow) & 7;       // logical 16B chunk (swizzle src)

  f32x4 acc[4][4] = {};
  for (int kt = 0; kt < Kd; kt += 64) {
#pragma unroll
    for (int i = 0; i < 4; i++) {
      const int r = wave * 32 + i * 8;              // r % 8 == 0
      __builtin_amdgcn_global_load_lds(
          GLOBAL_AS(&A[(size_t)(m0 + r + srow) * Kd + kt + schunk * 8]),
          LDS_AS(&As[r][0]), 16, 0, 0);
      __builtin_amdgcn_global_load_lds(
          GLOBAL_AS(&W[(size_t)(n0 + r + srow) * Kd + kt + schunk * 8]),
          LDS_AS(&Bs[r][0]), 16, 0, 0);
    }
    __syncthreads();
#pragma unroll
    for (int ks = 0; ks < 2; ks++) {
      const int col = (((ks * 4 + quad + l16) & 7)) * 8;   // swizzled read chunk
      bf16x8 af[4], bfr[4];
#pragma unroll
      for (int t = 0; t < 4; t++)
        af[t] = *reinterpret_cast<const bf16x8*>(&As[wm + t * 16 + l16][col]);
#pragma unroll
      for (int t = 0; t < 4; t++)
        bfr[t] = *reinterpret_cast<const bf16x8*>(&Bs[wn + t * 16 + l16][col]);
#pragma unroll
      for (int tm = 0; tm < 4; tm++)
#pragma unroll
        for (int tn = 0; tn < 4; tn++)
          acc[tm][tn] = __builtin_amdgcn_mfma_f32_16x16x32_bf16(af[tm], bfr[tn], acc[tm][tn], 0, 0, 0);
    }
    __syncthreads();
  }
#pragma unroll
  for (int tm = 0; tm < 4; tm++) {
#pragma unroll
    for (int tn = 0; tn < 4; tn++) {
      const int row0 = m0 + wm + tm * 16 + quad * 4;
      if constexpr (MODE == MODE_OUT) {
        const int col = n0 + wn + tn * 16 + l16;
#pragma unroll
        for (int j = 0; j < 4; j++)
          Oout[(size_t)(row0 + j) * DMODEL + col] = acc[tm][tn][j];
      } else {
        const int mat = n0 >> 11;              // 0=Q 1=K 2=V
        const int col = (n0 & 2047) + wn + tn * 16 + l16;
        const int h = col >> 7, dd = col & 127;
        if (mat == 2) {
          const int b = row0 >> 11, s = row0 & 2047;
          bf16x4 pk;
#pragma unroll
          for (int j = 0; j < 4; j++) pk[j] = (bf16)acc[tm][tn][j];
          *reinterpret_cast<bf16x4*>(&Ov[((size_t)(b * NH + h) * HD + dd) * SEQ + s]) = pk;
        } else {
          bf16* O = mat ? Ok : Oq;
          const float scale = mat ? 1.0f : 0.12751745f;   // (1/sqrt(128)) * log2(e)
#pragma unroll
          for (int j = 0; j < 4; j++) {
            const int row = row0 + j;
            const int b = row >> 11, s = row & 2047;
            O[((size_t)(b * NH + h) * SEQ + s) * HD + dd] = (bf16)(acc[tm][tn][j] * scale);
          }
        }
      }
    }
  }
}

// ---------------- flash attention: R1 anchor structure (QBLK=64, dbuf) ----------
// Only change vs the measured 357.7us kernel: softmax in exp2 domain (Q carries
// log2(e) from the projection scale), so __expf -> exp2f (saves the v_mul-by-
// log2e each exp expands to; 17 VALU/lane/iter off the 27%-busy VALU path).
__global__ __launch_bounds__(256, 2) void attn_kernel(
    const bf16* __restrict__ Q, const bf16* __restrict__ K,
    const bf16* __restrict__ Vt, bf16* __restrict__ Y) {
  const int j = blockIdx.x;          // 0..15
  const int bh = blockIdx.y;
  __shared__ __align__(16) char smem[74752];
  auto Ks0 = (bf16(*)[128])(smem);              // [64][128] 16384 B (swizzled)
  auto Ks1 = (bf16(*)[128])(smem + 16384);
  auto Vt0 = (bf16(*)[64])(smem + 32768);       // [128][64] 16384 B (swizzled)
  auto Vt1 = (bf16(*)[64])(smem + 49152);
  auto Ps  = (bf16(*)[16][72])(smem + 65536);   // [4][16][72] 9216 B (padded)
  const int tid = threadIdx.x;
  const int wave = tid >> 6;
  const int lane = tid & 63;
  const int quad = lane >> 4;
  const int l16 = lane & 15;

  const bf16* Kbh = K + (size_t)bh * SEQ * HD;
  const bf16* Vbh = Vt + (size_t)bh * HD * SEQ;
  const int b = bh >> 4, h = bh & 15;

  const int krow = lane >> 4;
  const int vrow = lane >> 3;
  const int vchunk = ((lane & 7) - vrow) & 7;

  auto stageK = [&](int kt, bf16 (*Kd)[128]) {
#pragma unroll
    for (int i = 0; i < 4; i++) {
      const int rbase = wave * 16 + i * 4;
      const int r = rbase + krow;
      const int c = ((lane & 15) - krow - i * 4) & 15;
      __builtin_amdgcn_global_load_lds(
          GLOBAL_AS(&Kbh[(size_t)(kt + r) * HD + c * 8]), LDS_AS(&Kd[rbase][0]), 16, 0, 0);
    }
  };
  auto stageV = [&](int kt, bf16 (*Vd)[64]) {
#pragma unroll
    for (int i = 0; i < 4; i++) {
      const int rbase = wave * 32 + i * 8;
      const int r = rbase + vrow;
      __builtin_amdgcn_global_load_lds(
          GLOBAL_AS(&Vbh[(size_t)r * SEQ + kt + vchunk * 8]), LDS_AS(&Vd[rbase][0]), 16, 0, 0);
    }
  };

  for (int pass = 0; pass < 2; ++pass) {
    const int qt = pass ? (31 - j) : j;
    const int q0 = qt * 64;
    const int ntiles = qt + 1;

    const bf16* Qw = Q + ((size_t)bh * SEQ + q0 + wave * 16) * HD;
    bf16x8 qf[4];
#pragma unroll
    for (int kk = 0; kk < 4; kk++)
      qf[kk] = *reinterpret_cast<const bf16x8*>(&Qw[(size_t)l16 * HD + kk * 32 + quad * 8]);

    f32x4 oacc[8] = {};
    float m_i = -3.0e38f, l_i = 0.f;

    // prologue: stage tile 0 into buf0, drain, sync
    stageK(0, Ks0);
    stageV(0, Vt0);
    asm volatile("s_waitcnt vmcnt(0)" ::: "memory");
    __builtin_amdgcn_s_barrier();
    __builtin_amdgcn_sched_barrier(0);

    for (int t = 0; t < ntiles; ++t) {
      bf16 (*Ksc)[128] = (t & 1) ? Ks1 : Ks0;
      bf16 (*Vtc)[64]  = (t & 1) ? Vt1 : Vt0;
      // issue next tile's stage into the other buffer BEFORE compute
      if (t + 1 < ntiles) {
        bf16 (*Ksn)[128] = (t & 1) ? Ks0 : Ks1;
        bf16 (*Vtn)[64]  = (t & 1) ? Vt0 : Vt1;
        stageK((t + 1) * 64, Ksn);
        stageV((t + 1) * 64, Vtn);
      }

      f32x4 sacc[4] = {};
#pragma unroll
      for (int kk = 0; kk < 4; kk++) {
        const int kcol = (((kk * 4 + quad + l16) & 15)) * 8;
        bf16x8 ka[4];
#pragma unroll
        for (int mt = 0; mt < 4; mt++)
          ka[mt] = *reinterpret_cast<const bf16x8*>(&Ksc[mt * 16 + l16][kcol]);
#pragma unroll
        for (int mt = 0; mt < 4; mt++)
          sacc[mt] = __builtin_amdgcn_mfma_f32_16x16x32_bf16(ka[mt], qf[kk], sacc[mt], 0, 0, 0);
      }

      const int qg_loc = wave * 16 + l16;
      float mx = -3.0e38f;
      if (t == ntiles - 1) {
#pragma unroll
        for (int mt = 0; mt < 4; mt++)
#pragma unroll
          for (int jj = 0; jj < 4; jj++) {
            const int kg = mt * 16 + quad * 4 + jj;
            float v = (kg <= qg_loc) ? sacc[mt][jj] : -3.0e38f;
            sacc[mt][jj] = v;
            mx = fmaxf(mx, v);
          }
      } else {
#pragma unroll
        for (int mt = 0; mt < 4; mt++)
#pragma unroll
          for (int jj = 0; jj < 4; jj++) mx = fmaxf(mx, sacc[mt][jj]);
      }
      mx = fmaxf(mx, __shfl_xor(mx, 16));
      mx = fmaxf(mx, __shfl_xor(mx, 32));
      const float mnew = fmaxf(m_i, mx);
      const float alpha = exp2f(m_i - mnew);    // log2-domain (Q carries log2e)
      m_i = mnew;
      float rs = 0.f;
#pragma unroll
      for (int mt = 0; mt < 4; mt++)
#pragma unroll
        for (int jj = 0; jj < 4; jj++) {
          float p = exp2f(sacc[mt][jj] - mnew);
          sacc[mt][jj] = p;
          rs += p;
        }
      rs += __shfl_xor(rs, 16);
      rs += __shfl_xor(rs, 32);
      l_i = l_i * alpha + rs;
#pragma unroll
      for (int mt8 = 0; mt8 < 8; mt8++)
#pragma unroll
        for (int jj = 0; jj < 4; jj++) oacc[mt8][jj] *= alpha;

#pragma unroll
      for (int mt = 0; mt < 4; mt++) {
        bf16x4 pk;
#pragma unroll
        for (int jj = 0; jj < 4; jj++) pk[jj] = (bf16)sacc[mt][jj];
        *reinterpret_cast<bf16x4*>(&Ps[wave][l16][mt * 16 + quad * 4]) = pk;
      }

#pragma unroll
      for (int kk2 = 0; kk2 < 2; kk2++) {
        const int vcol = ((kk2 * 4 + quad + l16) & 7) * 8;
        bf16x8 pb = *reinterpret_cast<const bf16x8*>(&Ps[wave][l16][kk2 * 32 + quad * 8]);
#pragma unroll
        for (int mt8 = 0; mt8 < 8; mt8++) {
          bf16x8 av = *reinterpret_cast<const bf16x8*>(&Vtc[mt8 * 16 + l16][vcol]);
          oacc[mt8] = __builtin_amdgcn_mfma_f32_16x16x32_bf16(av, pb, oacc[mt8], 0, 0, 0);
        }
      }

      // drain this iter's prefetch, then sync
      asm volatile("s_waitcnt vmcnt(0)" ::: "memory");
      __builtin_amdgcn_s_barrier();
      __builtin_amdgcn_sched_barrier(0);
    }

    const float inv = 1.0f / l_i;
    const int qg = q0 + wave * 16 + l16;
#pragma unroll
    for (int mt8 = 0; mt8 < 8; mt8++) {
      bf16x4 pk;
#pragma unroll
      for (int jj = 0; jj < 4; jj++) pk[jj] = (bf16)(oacc[mt8][jj] * inv);
      *reinterpret_cast<bf16x4*>(
          &Y[(size_t)(b * SEQ + qg) * DMODEL + h * HD + mt8 * 16 + quad * 4]) = pk;
    }
  }
}

// ---------------- launch ----------------
extern "C" void kernel_launch(void* const* d_in, const int* in_sizes, int n_in,
                              void* d_out, int out_size, void* d_ws, size_t ws_size,
                              hipStream_t stream) {
  const float* x  = (const float*)d_in[0];
  const float* Wq = (const float*)d_in[2];
  const float* Wk = (const float*)d_in[3];
  const float* Wv = (const float*)d_in[4];
  const float* Wo = (const float*)d_in[5];
  float* out = (float*)d_out;

  char* ws = (char*)d_ws;
  bf16* xb  = (bf16*)(ws + 0);
  bf16* Wqb = (bf16*)(ws + 16777216);    // Wq,Wk,Wv contiguous -> one [6144][2048]
  bf16* Wob = (bf16*)(ws + 41943040);
  bf16* Qb  = (bf16*)(ws + 50331648);    // [B,H,S,d]
  bf16* Kb  = (bf16*)(ws + 67108864);    // [B,H,S,d]
  bf16* Vtb = (bf16*)(ws + 83886080);    // [B,H,d,S]
  bf16* Yb  = xb;                        // [B,S,D] (x dead after projections)
  if (ws_size < 100663296) return;

  // one fused convert: 6,291,456 float4 groups -> 24576 blocks
  cvt5_kernel<<<24576, 256, 0, stream>>>(x, Wq, Wk, Wv, Wo, xb);

  gemm_bt<MODE_QKV><<<dim3(48, MROWS / 128), 256, 0, stream>>>(
      xb, Wqb, Qb, Kb, Vtb, nullptr);

  attn_kernel<<<dim3(16, BATCH * NH), 256, 0, stream>>>(Qb, Kb, Vtb, Yb);

  gemm_bt<MODE_OUT><<<dim3(16, MROWS / 128), 256, 0, stream>>>(
      Yb, Wob, nullptr, nullptr, nullptr, out);
}